// Round 5
// baseline (138.093 us; speedup 1.0000x reference)
//
#include <hip/hip_runtime.h>
#include <hip/hip_bf16.h>

#define B_ 16
#define H_ 128
#define L_ 4096
#define N_ 64
#define DT_ 0.01f

typedef __bf16 bf16;
typedef __bf16 bf16x8 __attribute__((ext_vector_type(8)));
typedef __bf16 bf16x4 __attribute__((ext_vector_type(4)));
typedef float f32x4 __attribute__((ext_vector_type(4)));

// ---------------------------------------------------------------- k_prep ----
// One block per h (128 blocks, 64 threads). Builds tables + casts weights.
//  Pbf[h][row][j] (A-op, 128x64): row n: Re(A^{63-j}), row 64+n: Im(A^{63-j})
//  Qbf[h][dlt][k] (A-op, 64x128): k=2n: Re(W*A^{dlt+1}), k=2n+1: -Im(...)
//  tap[h][dlt] = sum_n Re(W_n A_n^dlt);  acre/acim = A^64
__global__ __launch_bounds__(64) void k_prep(
        const float* __restrict__ lre, const float* __restrict__ lim,
        const float* __restrict__ wre, const float* __restrict__ wim,
        const float* __restrict__ w1, const float* __restrict__ w2,
        bf16* __restrict__ w1b, bf16* __restrict__ w2b,
        bf16* __restrict__ Pbf, bf16* __restrict__ Qbf,
        float* __restrict__ tap, float* __restrict__ acre, float* __restrict__ acim) {
    __shared__ bf16  Pl[128 * 72];
    __shared__ bf16  Ql[64 * 136];
    __shared__ float red[64 * 65];

    const int h = blockIdx.x, n = threadIdx.x;

    w1b[h * H_ + n]      = (bf16)w1[h * H_ + n];
    w1b[h * H_ + 64 + n] = (bf16)w1[h * H_ + 64 + n];
    w2b[h * H_ + n]      = (bf16)w2[h * H_ + n];
    w2b[h * H_ + 64 + n] = (bf16)w2[h * H_ + 64 + n];

    const float lr = lre[h * 64 + n] * DT_, li = lim[h * 64 + n] * DT_;
    const float e = expf(lr);
    const float ar = e * cosf(li), ai = e * sinf(li);
    const float wr = wre[h * 64 + n], wi = wim[h * 64 + n];
    const float war = wr * ar - wi * ai;
    const float wai = wr * ai + wi * ar;
    float pr = 1.f, pi = 0.f;
    for (int dlt = 0; dlt < 64; ++dlt) {
        Pl[n * 72 + (63 - dlt)]        = (bf16)pr;
        Pl[(64 + n) * 72 + (63 - dlt)] = (bf16)pi;
        Ql[dlt * 136 + 2 * n]     = (bf16)(war * pr - wai * pi);
        Ql[dlt * 136 + 2 * n + 1] = (bf16)(-(war * pi + wai * pr));
        red[dlt * 65 + n] = wr * pr - wi * pi;
        const float npr = ar * pr - ai * pi;
        const float npi = ar * pi + ai * pr;
        pr = npr; pi = npi;
    }
    acre[h * 64 + n] = pr;
    acim[h * 64 + n] = pi;
    __syncthreads();

    float s = 0.f;
    #pragma unroll
    for (int k = 0; k < 64; ++k) s += red[n * 65 + k];
    tap[h * 64 + n] = s;

    bf16* Ph = Pbf + (size_t)h * 128 * 64;
    bf16* Qh = Qbf + (size_t)h * 64 * 128;
    #pragma unroll
    for (int i = 0; i < 16; ++i) {
        const int flat = i * 512 + n * 8;
        {
            const int row = flat >> 6, col = flat & 63;
            *(bf16x8*)(Ph + flat) = *(const bf16x8*)(&Pl[row * 72 + col]);
        }
        {
            const int row = flat >> 7, col = flat & 127;
            *(bf16x8*)(Qh + flat) = *(const bf16x8*)(&Ql[row * 136 + col]);
        }
    }
}

// ---------------------------------------------------------------- k_ssm2 ----
// Chunked scan, block = (b,h), 8 waves (512 threads). C=64 chunks of 64.
// (r3 version verbatim — last known-good.)
#define USWZ(c, k) ((c) * 64 + (((((k) >> 4) ^ ((c) & 3)) << 4) | ((k) & 15)))
#define SSWZ(c, k) ((c) * 128 + (((((k) >> 4) ^ ((c) & 7)) << 4) | ((k) & 15)))
__global__ __launch_bounds__(512, 4) void k_ssm2(
        const float* __restrict__ u, const float* __restrict__ dv,
        const bf16* __restrict__ Pbf, const bf16* __restrict__ Qbf,
        const float* __restrict__ tap,
        const float* __restrict__ acre, const float* __restrict__ acim,
        bf16* __restrict__ ybf) {
    __shared__ bf16  Ubf[64 * 64];     //  8 KB
    __shared__ float Ctr[128 * 65];    // 32.5 KB (aliased as Yb stride-72 later)
    __shared__ bf16  Sbf[64 * 128];    // 16 KB
    __shared__ bf16  Tm[64 * 72];      //  9 KB

    const int tid = threadIdx.x;
    const int bh  = blockIdx.x;
    const int h   = bh & (H_ - 1);
    const float* __restrict__ up = u + (size_t)bh * L_;

    // ---- stage u (fully coalesced) -> Ubf bf16 swizzled ----
    {
        const int c = tid >> 3, j0 = (tid & 7) << 3;
        const float4* src = (const float4*)(up + c * 64 + j0);
        float4 f0 = src[0], f1 = src[1];
        bf16x8 t;
        t[0] = (bf16)f0.x; t[1] = (bf16)f0.y; t[2] = (bf16)f0.z; t[3] = (bf16)f0.w;
        t[4] = (bf16)f1.x; t[5] = (bf16)f1.y; t[6] = (bf16)f1.z; t[7] = (bf16)f1.w;
        *(bf16x8*)(&Ubf[USWZ(c, j0)]) = t;
    }
    // ---- Toeplitz T[dlt][j] = tap[dlt-j] (+d on diag) ----
    {
        const int dlt = tid >> 3, j0 = (tid & 7) << 3;
        const float* tp = tap + h * 64;
        const float dh = dv[h];
        bf16x8 t;
        #pragma unroll
        for (int e = 0; e < 8; ++e) {
            const int j = j0 + e;
            float v = (j <= dlt) ? tp[dlt - j] : 0.f;
            if (j == dlt) v += dh;
            t[e] = (bf16)v;
        }
        *(bf16x8*)(&Tm[dlt * 72 + j0]) = t;
    }
    __syncthreads();

    const int lane = tid & 63, wv = tid >> 6;        // wv in [0,8)
    const int cl = lane & 15, q = lane >> 4;

    // ---- MFMA-1: Ctr[row][c] = P @ U; wave wv owns rows [16wv,16wv+16) ----
    {
        f32x4 acc[4];
        #pragma unroll
        for (int nt = 0; nt < 4; ++nt) acc[nt] = (f32x4){0.f, 0.f, 0.f, 0.f};
        const bf16* Ph = Pbf + (size_t)h * 128 * 64;
        #pragma unroll
        for (int ks = 0; ks < 2; ++ks) {
            const int k0 = ks * 32 + q * 8;
            const bf16x8 a = *(const bf16x8*)(Ph + (size_t)(wv * 16 + cl) * 64 + k0);
            #pragma unroll
            for (int nt = 0; nt < 4; ++nt) {
                const int c = nt * 16 + cl;
                const bf16x8 bfr = *(const bf16x8*)(&Ubf[USWZ(c, k0)]);
                acc[nt] = __builtin_amdgcn_mfma_f32_16x16x32_bf16(a, bfr, acc[nt], 0, 0, 0);
            }
        }
        #pragma unroll
        for (int nt = 0; nt < 4; ++nt)
            #pragma unroll
            for (int r = 0; r < 4; ++r)
                Ctr[(wv * 16 + q * 4 + r) * 65 + nt * 16 + cl] = acc[nt][r];
    }
    __syncthreads();

    // ---- scan (wave 0): states entering each chunk ----
    if (wv == 0) {
        const int n = lane;
        const float ar = acre[h * 64 + n], ai = acim[h * 64 + n];
        float sr = 0.f, si = 0.f;
        #pragma unroll 8
        for (int c = 0; c < 64; ++c) {
            bf16* sp = &Sbf[SSWZ(c, 2 * n)];
            sp[0] = (bf16)sr;
            sp[1] = (bf16)si;
            const float cr = Ctr[n * 65 + c];
            const float ci = Ctr[(64 + n) * 65 + c];
            const float nr = fmaf(ar, sr, fmaf(-ai, si, cr));
            const float ni = fmaf(ar, si, fmaf(ai, sr, ci));
            sr = nr; si = ni;
        }
    }
    __syncthreads();

    // ---- MFMA-2: y[dlt][c] = Q@S + T@U; wave wv -> m-tile wv>>1, n-tiles (wv&1)*2+{0,1}
    {
        const int mt  = wv >> 1;
        const int nt0 = (wv & 1) * 2;
        f32x4 acc[2];
        acc[0] = (f32x4){0.f, 0.f, 0.f, 0.f};
        acc[1] = (f32x4){0.f, 0.f, 0.f, 0.f};
        const bf16* Qh = Qbf + (size_t)h * 64 * 128;
        #pragma unroll
        for (int ks = 0; ks < 4; ++ks) {
            const int k0 = ks * 32 + q * 8;
            const bf16x8 a = *(const bf16x8*)(Qh + (size_t)(mt * 16 + cl) * 128 + k0);
            #pragma unroll
            for (int j = 0; j < 2; ++j) {
                const int c = (nt0 + j) * 16 + cl;
                const bf16x8 bfr = *(const bf16x8*)(&Sbf[SSWZ(c, k0)]);
                acc[j] = __builtin_amdgcn_mfma_f32_16x16x32_bf16(a, bfr, acc[j], 0, 0, 0);
            }
        }
        #pragma unroll
        for (int ks = 0; ks < 2; ++ks) {
            const int k0 = ks * 32 + q * 8;
            const bf16x8 a = *(const bf16x8*)(&Tm[(mt * 16 + cl) * 72 + k0]);
            #pragma unroll
            for (int j = 0; j < 2; ++j) {
                const int c = (nt0 + j) * 16 + cl;
                const bf16x8 bfr = *(const bf16x8*)(&Ubf[USWZ(c, k0)]);
                acc[j] = __builtin_amdgcn_mfma_f32_16x16x32_bf16(a, bfr, acc[j], 0, 0, 0);
            }
        }
        // Yb[c][dlt] stride 72 (16B-aligned), aliasing Ctr (dead after scan)
        bf16* Yb = (bf16*)Ctr;
        #pragma unroll
        for (int j = 0; j < 2; ++j) {
            const int c = (nt0 + j) * 16 + cl;
            bf16x4 yv;
            #pragma unroll
            for (int r = 0; r < 4; ++r) yv[r] = (bf16)acc[j][r];
            *(bf16x4*)(&Yb[c * 72 + mt * 16 + q * 4]) = yv;
        }
    }
    __syncthreads();

    // ---- coalesced store: one bf16x8 per thread ----
    {
        const bf16* Yb = (const bf16*)Ctr;
        const int c = tid >> 3, s0 = (tid & 7) << 3;
        bf16x8 v = *(const bf16x8*)(&Yb[c * 72 + s0]);
        *(bf16x8*)(ybf + (size_t)bh * L_ + c * 64 + s0) = v;
    }
}

// ----------------------------------------------------------------- k_mlp ----
// Fused 2-layer MLP. r3 body; NEW epilogue: fp32 LDS tile [o][l] (stride 68)
// + fully-coalesced float4 row stores (8 dwordx4/thread vs 32 scalar stores).
#define YSTR 136
__global__ __launch_bounds__(256, 4) void k_mlp(
        const bf16* __restrict__ ybf,
        const bf16* __restrict__ w1b, const bf16* __restrict__ w2b,
        const float* __restrict__ b1, const float* __restrict__ b2,
        float* __restrict__ out) {
    __shared__ float Ys[128 * 68];    // 34.8 KB fp32 out tile [o][l]
    __shared__ float B1s[H_], B2s[H_];
    bf16* YT = (bf16*)Ys;             // aliased: y tile [l][h] stride YSTR (17.4 KB), then H1T

    const int tid = threadIdx.x;
    const int b   = blockIdx.x >> 6;
    const int lt  = blockIdx.x & 63;
    const int l0  = lt * 64;

    if (tid < H_) { B1s[tid] = b1[tid]; B2s[tid] = b2[tid]; }

    // ---- stage y tile transposed [l][h] ----
    {
        const int h  = tid >> 1;
        const int lh = (tid & 1) * 32;
        const bf16x8* src = (const bf16x8*)(ybf + ((size_t)b * H_ + h) * L_ + l0 + lh);
        #pragma unroll
        for (int v = 0; v < 4; ++v) {
            bf16x8 d = src[v];
            #pragma unroll
            for (int e = 0; e < 8; ++e) YT[(lh + v * 8 + e) * YSTR + h] = d[e];
        }
    }
    __syncthreads();

    const int lane = tid & 63;
    const int wv   = tid >> 6;
    const int m    = lane & 15;
    const int q    = lane >> 4;
    const int m0   = wv * 32;

    // ---- layer 1 ----
    f32x4 acc[2][4];
    #pragma unroll
    for (int i = 0; i < 2; ++i)
        #pragma unroll
        for (int nt = 0; nt < 4; ++nt) acc[i][nt] = (f32x4){0.f, 0.f, 0.f, 0.f};

    #pragma unroll
    for (int kb = 0; kb < 4; ++kb) {
        const bf16x8 a0 = *(const bf16x8*)(w1b + (size_t)(m0 + m)      * H_ + kb * 32 + q * 8);
        const bf16x8 a1 = *(const bf16x8*)(w1b + (size_t)(m0 + 16 + m) * H_ + kb * 32 + q * 8);
        #pragma unroll
        for (int nt = 0; nt < 4; ++nt) {
            const bf16x8 bfr = *(const bf16x8*)(&YT[(nt * 16 + m) * YSTR + kb * 32 + q * 8]);
            acc[0][nt] = __builtin_amdgcn_mfma_f32_16x16x32_bf16(a0, bfr, acc[0][nt], 0, 0, 0);
            acc[1][nt] = __builtin_amdgcn_mfma_f32_16x16x32_bf16(a1, bfr, acc[1][nt], 0, 0, 0);
        }
    }
    __syncthreads();   // all YT reads done before H1T(=YT) writes

    #pragma unroll
    for (int i = 0; i < 2; ++i) {
        const int o0 = m0 + 16 * i + 4 * q;
        #pragma unroll
        for (int nt = 0; nt < 4; ++nt) {
            const f32x4 v = acc[i][nt];
            bf16x4 hv;
            #pragma unroll
            for (int r = 0; r < 4; ++r) {
                float x = v[r] + B1s[o0 + r];
                hv[r] = (bf16)fmaxf(x, 0.f);
            }
            *(bf16x4*)(&YT[(nt * 16 + m) * YSTR + o0]) = hv;
        }
    }
    __syncthreads();

    // ---- layer 2 ----
    f32x4 acc2[2][4];
    #pragma unroll
    for (int i = 0; i < 2; ++i)
        #pragma unroll
        for (int nt = 0; nt < 4; ++nt) acc2[i][nt] = (f32x4){0.f, 0.f, 0.f, 0.f};

    #pragma unroll
    for (int kb = 0; kb < 4; ++kb) {
        const bf16x8 a0 = *(const bf16x8*)(w2b + (size_t)(m0 + m)      * H_ + kb * 32 + q * 8);
        const bf16x8 a1 = *(const bf16x8*)(w2b + (size_t)(m0 + 16 + m) * H_ + kb * 32 + q * 8);
        #pragma unroll
        for (int nt = 0; nt < 4; ++nt) {
            const bf16x8 bfr = *(const bf16x8*)(&YT[(nt * 16 + m) * YSTR + kb * 32 + q * 8]);
            acc2[0][nt] = __builtin_amdgcn_mfma_f32_16x16x32_bf16(a0, bfr, acc2[0][nt], 0, 0, 0);
            acc2[1][nt] = __builtin_amdgcn_mfma_f32_16x16x32_bf16(a1, bfr, acc2[1][nt], 0, 0, 0);
        }
    }
    __syncthreads();   // all H1T(=Ys) reads done before Ys fp32 writes

    // ---- epilogue: bias + relu -> Ys[o][l] (stride 68, bank-balanced) ----
    #pragma unroll
    for (int i = 0; i < 2; ++i) {
        const int o0 = m0 + 16 * i + 4 * q;
        #pragma unroll
        for (int nt = 0; nt < 4; ++nt) {
            const f32x4 v = acc2[i][nt];
            #pragma unroll
            for (int r = 0; r < 4; ++r) {
                float x = v[r] + B2s[o0 + r];
                Ys[(o0 + r) * 68 + nt * 16 + m] = fmaxf(x, 0.f);
            }
        }
    }
    __syncthreads();

    // ---- coalesced float4 stores: 16 rows/pass x 8 passes ----
    {
        const int rg = tid >> 4, c4 = (tid & 15) << 2;
        float* op = out + ((size_t)b * H_) * L_ + l0;
        #pragma unroll
        for (int v = 0; v < 8; ++v) {
            const int row = v * 16 + rg;
            const float4 val = *(const float4*)(&Ys[row * 68 + c4]);
            *(float4*)(op + (size_t)row * L_ + c4) = val;
        }
    }
}

// ---------------------------------------------------------------- launch ----
extern "C" void kernel_launch(void* const* d_in, const int* in_sizes, int n_in,
                              void* d_out, int out_size, void* d_ws, size_t ws_size,
                              hipStream_t stream) {
    const float* u   = (const float*)d_in[0];
    const float* lre = (const float*)d_in[1];
    const float* lim = (const float*)d_in[2];
    const float* wre = (const float*)d_in[3];
    const float* wim = (const float*)d_in[4];
    const float* dv  = (const float*)d_in[5];
    const float* w1  = (const float*)d_in[6];
    const float* b1  = (const float*)d_in[7];
    const float* w2  = (const float*)d_in[8];
    const float* b2  = (const float*)d_in[9];
    float* out = (float*)d_out;

    char* ws = (char*)d_ws;
    bf16*  ybf  = (bf16*)ws;                 ws += (size_t)B_ * H_ * L_ * 2;
    bf16*  w1b  = (bf16*)ws;                 ws += H_ * H_ * 2;
    bf16*  w2b  = (bf16*)ws;                 ws += H_ * H_ * 2;
    bf16*  Pbf  = (bf16*)ws;                 ws += (size_t)H_ * 128 * 64 * 2;
    bf16*  Qbf  = (bf16*)ws;                 ws += (size_t)H_ * 64 * 128 * 2;
    float* tap  = (float*)ws;                ws += H_ * 64 * 4;
    float* acre = (float*)ws;                ws += H_ * 64 * 4;
    float* acim = (float*)ws;                ws += H_ * 64 * 4;

    hipLaunchKernelGGL(k_prep, dim3(H_), dim3(64), 0, stream,
                       lre, lim, wre, wim, w1, w2, w1b, w2b,
                       Pbf, Qbf, tap, acre, acim);
    hipLaunchKernelGGL(k_ssm2, dim3(B_ * H_), dim3(512), 0, stream,
                       u, dv, Pbf, Qbf, tap, acre, acim, ybf);
    hipLaunchKernelGGL(k_mlp, dim3(B_ * (L_ / 64)), dim3(256), 0, stream,
                       ybf, w1b, w2b, b1, b2, out);
}

// Round 7
// 131.201 us; speedup vs baseline: 1.0525x; 1.0525x over previous
//
#include <hip/hip_runtime.h>
#include <hip/hip_bf16.h>

#define B_ 16
#define H_ 128
#define L_ 4096
#define N_ 64
#define DT_ 0.01f

typedef __bf16 bf16;
typedef __bf16 bf16x8 __attribute__((ext_vector_type(8)));
typedef __bf16 bf16x4 __attribute__((ext_vector_type(4)));
typedef float f32x4 __attribute__((ext_vector_type(4)));

#define USWZ(c, k) ((c) * 64 + (((((k) >> 4) ^ ((c) & 3)) << 4) | ((k) & 15)))
#define SSWZ(c, k) ((c) * 128 + (((((k) >> 4) ^ ((c) & 7)) << 4) | ((k) & 15)))

// ---------------------------------------------------------------- k_ssm3 ----
// 512 blocks x 512 threads. Block = (h, bgroup of 4 batches). No tables:
// P/Q MFMA A-fragments computed closed-form (A^d = exp(d*DT*lambda)) into
// registers once per block; taps via shfl-reduce; Toeplitz in LDS.
// Also performs the W1/W2 bf16 cast (64 elements per block).
__global__ __launch_bounds__(512, 4) void k_ssm3(
        const float* __restrict__ u,
        const float* __restrict__ lre, const float* __restrict__ lim,
        const float* __restrict__ wre, const float* __restrict__ wim,
        const float* __restrict__ dv,
        const float* __restrict__ w1, const float* __restrict__ w2,
        bf16* __restrict__ w1b, bf16* __restrict__ w2b,
        bf16* __restrict__ ybf) {
    alignas(16) __shared__ char smem[68352];
    bf16*  Ubf  = (bf16*)smem;                    //  8192 B
    float* Ctr  = (float*)(smem + 8192);          // 33280 B (aliased as Yb bf16 stride-72)
    bf16*  Sbf  = (bf16*)(smem + 41472);          // 16384 B
    bf16*  Tm   = (bf16*)(smem + 57856);          //  9216 B
    float* lamS = (float*)(smem + 67072);         //  1024 B: [lr|li|wr|wi][64] (lr,li pre-scaled by DT)
    float* taps = (float*)(smem + 68096);         //   256 B

    const int tid  = threadIdx.x;
    const int lane = tid & 63, wv = tid >> 6;     // wv in [0,8)
    const int cl   = lane & 15, q = lane >> 4;
    const int bId  = blockIdx.x;
    const int h    = bId & 127;
    const int bg   = bId >> 7;                    // [0,4)

    // ---- weight cast: 64 contiguous elements per block ----
    if (tid < 64) {
        if (bId < 256) w1b[bId * 64 + tid] = (bf16)w1[bId * 64 + tid];
        else           w2b[(bId - 256) * 64 + tid] = (bf16)w2[(bId - 256) * 64 + tid];
    }
    // ---- stage lambda/W for this h ----
    if (tid < 64) {
        lamS[tid]       = lre[h * 64 + tid] * DT_;
        lamS[64 + tid]  = lim[h * 64 + tid] * DT_;
        lamS[128 + tid] = wre[h * 64 + tid];
        lamS[192 + tid] = wim[h * 64 + tid];
    }
    __syncthreads();

    // ---- P fragments (MFMA-1 A-op) in regs: row = wv*16+cl ----
    bf16x8 pA0, pA1;
    {
        const int row = wv * 16 + cl;
        const int n = row & 63;
        const bool isIm = row >= 64;
        const float lr = lamS[n], li = lamS[64 + n];
        #pragma unroll
        for (int jj = 0; jj < 8; ++jj) {
            const float p0 = (float)(63 - (q * 8 + jj));
            const float e0 = __expf(p0 * lr);
            pA0[jj] = (bf16)(isIm ? e0 * __sinf(p0 * li) : e0 * __cosf(p0 * li));
            const float p1 = (float)(63 - (32 + q * 8 + jj));
            const float e1 = __expf(p1 * lr);
            pA1[jj] = (bf16)(isIm ? e1 * __sinf(p1 * li) : e1 * __cosf(p1 * li));
        }
    }
    // ---- Q fragments (MFMA-2 A-op) in regs: dlt = (wv>>1)*16+cl ----
    bf16x8 qA[4];
    {
        const float fd = (float)((wv >> 1) * 16 + cl + 1);   // dlt+1
        #pragma unroll
        for (int ks = 0; ks < 4; ++ks) {
            #pragma unroll
            for (int nn = 0; nn < 4; ++nn) {
                const int n = ks * 16 + q * 4 + nn;          // n = k>>1
                const float lr = lamS[n], li = lamS[64 + n];
                const float wr = lamS[128 + n], wi = lamS[192 + n];
                const float e  = __expf(fd * lr);
                const float cr = e * __cosf(fd * li), ci = e * __sinf(fd * li);
                qA[ks][2 * nn]     = (bf16)(wr * cr - wi * ci);
                qA[ks][2 * nn + 1] = (bf16)(-(wr * ci + wi * cr));
            }
        }
    }
    // ---- A^64 for the scan (lane = mode n) ----
    float a64r, a64i;
    {
        const float lr = lamS[lane], li = lamS[64 + lane];
        const float e = __expf(64.f * lr);
        a64r = e * __cosf(64.f * li);
        a64i = e * __sinf(64.f * li);
    }
    // ---- taps[dlt] = sum_n Re(W_n A_n^dlt): wave wv does dlt = wv*8+i ----
    {
        const float lr = lamS[lane], li = lamS[64 + lane];
        const float wr = lamS[128 + lane], wi = lamS[192 + lane];
        #pragma unroll
        for (int i = 0; i < 8; ++i) {
            const int dlt = wv * 8 + i;
            const float fd = (float)dlt;
            const float e = __expf(fd * lr);
            float t = wr * e * __cosf(fd * li) - wi * e * __sinf(fd * li);
            #pragma unroll
            for (int d = 1; d < 64; d <<= 1) t += __shfl_xor(t, d, 64);
            if (lane == 0) taps[dlt] = t;
        }
    }
    __syncthreads();

    // ---- Toeplitz Tm[dlt][j] = taps[dlt-j] (+d_h on diag) ----
    {
        const int dlt = tid >> 3, j0 = (tid & 7) << 3;
        const float dh = dv[h];
        bf16x8 t;
        #pragma unroll
        for (int e = 0; e < 8; ++e) {
            const int j = j0 + e;
            float v = (j <= dlt) ? taps[dlt - j] : 0.f;
            if (j == dlt) v += dh;
            t[e] = (bf16)v;
        }
        *(bf16x8*)(&Tm[dlt * 72 + j0]) = t;
    }

    // ---- 4 batches per block ----
    const int mt = wv >> 1, nt0 = (wv & 1) * 2;
    for (int it = 0; it < 4; ++it) {
        const int bh = (bg * 4 + it) * 128 + h;
        const float* __restrict__ up = u + (size_t)bh * L_;

        // stage u -> Ubf (coalesced float4 x2, bf16 swizzled)
        {
            const int c = tid >> 3, j0 = (tid & 7) << 3;
            const float4* src = (const float4*)(up + c * 64 + j0);
            const float4 f0 = src[0], f1 = src[1];
            bf16x8 t;
            t[0] = (bf16)f0.x; t[1] = (bf16)f0.y; t[2] = (bf16)f0.z; t[3] = (bf16)f0.w;
            t[4] = (bf16)f1.x; t[5] = (bf16)f1.y; t[6] = (bf16)f1.z; t[7] = (bf16)f1.w;
            *(bf16x8*)(&Ubf[USWZ(c, j0)]) = t;
        }
        __syncthreads();

        // MFMA-1: Ctr[row][c] = P @ U, wave wv owns rows [16wv,16wv+16)
        {
            f32x4 acc[4];
            #pragma unroll
            for (int nt = 0; nt < 4; ++nt) acc[nt] = (f32x4){0.f, 0.f, 0.f, 0.f};
            #pragma unroll
            for (int nt = 0; nt < 4; ++nt) {
                const int c = nt * 16 + cl;
                const bf16x8 b0 = *(const bf16x8*)(&Ubf[USWZ(c, q * 8)]);
                acc[nt] = __builtin_amdgcn_mfma_f32_16x16x32_bf16(pA0, b0, acc[nt], 0, 0, 0);
                const bf16x8 bq = *(const bf16x8*)(&Ubf[USWZ(c, 32 + q * 8)]);
                acc[nt] = __builtin_amdgcn_mfma_f32_16x16x32_bf16(pA1, bq, acc[nt], 0, 0, 0);
            }
            #pragma unroll
            for (int nt = 0; nt < 4; ++nt)
                #pragma unroll
                for (int r = 0; r < 4; ++r)
                    Ctr[(wv * 16 + q * 4 + r) * 65 + nt * 16 + cl] = acc[nt][r];
        }
        __syncthreads();

        // serial scan (wave 0): states entering each chunk
        if (wv == 0) {
            float sr = 0.f, si = 0.f;
            #pragma unroll 8
            for (int c = 0; c < 64; ++c) {
                bf16* sp = &Sbf[SSWZ(c, 2 * lane)];
                sp[0] = (bf16)sr;
                sp[1] = (bf16)si;
                const float cr = Ctr[lane * 65 + c];
                const float ci = Ctr[(64 + lane) * 65 + c];
                const float nr = fmaf(a64r, sr, fmaf(-a64i, si, cr));
                const float ni = fmaf(a64r, si, fmaf(a64i, sr, ci));
                sr = nr; si = ni;
            }
        }
        __syncthreads();

        // MFMA-2: y[dlt][c] = Q@S + T@U
        {
            f32x4 acc[2];
            acc[0] = (f32x4){0.f, 0.f, 0.f, 0.f};
            acc[1] = (f32x4){0.f, 0.f, 0.f, 0.f};
            #pragma unroll
            for (int ks = 0; ks < 4; ++ks) {
                const int k0 = ks * 32 + q * 8;
                #pragma unroll
                for (int j = 0; j < 2; ++j) {
                    const int c = (nt0 + j) * 16 + cl;
                    const bf16x8 bfr = *(const bf16x8*)(&Sbf[SSWZ(c, k0)]);
                    acc[j] = __builtin_amdgcn_mfma_f32_16x16x32_bf16(qA[ks], bfr, acc[j], 0, 0, 0);
                }
            }
            #pragma unroll
            for (int ks = 0; ks < 2; ++ks) {
                const int k0 = ks * 32 + q * 8;
                const bf16x8 a = *(const bf16x8*)(&Tm[(mt * 16 + cl) * 72 + k0]);
                #pragma unroll
                for (int j = 0; j < 2; ++j) {
                    const int c = (nt0 + j) * 16 + cl;
                    const bf16x8 bfr = *(const bf16x8*)(&Ubf[USWZ(c, k0)]);
                    acc[j] = __builtin_amdgcn_mfma_f32_16x16x32_bf16(a, bfr, acc[j], 0, 0, 0);
                }
            }
            bf16* Yb = (bf16*)Ctr;   // Ctr dead after scan
            #pragma unroll
            for (int j = 0; j < 2; ++j) {
                const int c = (nt0 + j) * 16 + cl;
                bf16x4 yv;
                #pragma unroll
                for (int r = 0; r < 4; ++r) yv[r] = (bf16)acc[j][r];
                *(bf16x4*)(&Yb[c * 72 + mt * 16 + q * 4]) = yv;
            }
        }
        __syncthreads();

        // coalesced y store (one bf16x8 per thread)
        {
            const bf16* Yb = (const bf16*)Ctr;
            const int c = tid >> 3, s0 = (tid & 7) << 3;
            const bf16x8 v = *(const bf16x8*)(&Yb[c * 72 + s0]);
            *(bf16x8*)(ybf + (size_t)bh * L_ + c * 64 + s0) = v;
        }
        __syncthreads();
    }
}

// ----------------------------------------------------------------- k_mlp ----
// r5 version verbatim (known-good). Fused 2-layer MLP, bf16 MFMA.
#define YSTR 136
__global__ __launch_bounds__(256, 4) void k_mlp(
        const bf16* __restrict__ ybf,
        const bf16* __restrict__ w1b, const bf16* __restrict__ w2b,
        const float* __restrict__ b1, const float* __restrict__ b2,
        float* __restrict__ out) {
    __shared__ float Ys[128 * 68];    // 34.8 KB fp32 out tile [o][l]
    __shared__ float B1s[H_], B2s[H_];
    bf16* YT = (bf16*)Ys;             // aliased: y tile [l][h] stride YSTR, then H1T

    const int tid = threadIdx.x;
    const int b   = blockIdx.x >> 6;
    const int lt  = blockIdx.x & 63;
    const int l0  = lt * 64;

    if (tid < H_) { B1s[tid] = b1[tid]; B2s[tid] = b2[tid]; }

    // ---- stage y tile transposed [l][h] ----
    {
        const int h  = tid >> 1;
        const int lh = (tid & 1) * 32;
        const bf16x8* src = (const bf16x8*)(ybf + ((size_t)b * H_ + h) * L_ + l0 + lh);
        #pragma unroll
        for (int v = 0; v < 4; ++v) {
            bf16x8 d = src[v];
            #pragma unroll
            for (int e = 0; e < 8; ++e) YT[(lh + v * 8 + e) * YSTR + h] = d[e];
        }
    }
    __syncthreads();

    const int lane = tid & 63;
    const int wv   = tid >> 6;
    const int m    = lane & 15;
    const int q    = lane >> 4;
    const int m0   = wv * 32;

    // ---- layer 1 ----
    f32x4 acc[2][4];
    #pragma unroll
    for (int i = 0; i < 2; ++i)
        #pragma unroll
        for (int nt = 0; nt < 4; ++nt) acc[i][nt] = (f32x4){0.f, 0.f, 0.f, 0.f};

    #pragma unroll
    for (int kb = 0; kb < 4; ++kb) {
        const bf16x8 a0 = *(const bf16x8*)(w1b + (size_t)(m0 + m)      * H_ + kb * 32 + q * 8);
        const bf16x8 a1 = *(const bf16x8*)(w1b + (size_t)(m0 + 16 + m) * H_ + kb * 32 + q * 8);
        #pragma unroll
        for (int nt = 0; nt < 4; ++nt) {
            const bf16x8 bfr = *(const bf16x8*)(&YT[(nt * 16 + m) * YSTR + kb * 32 + q * 8]);
            acc[0][nt] = __builtin_amdgcn_mfma_f32_16x16x32_bf16(a0, bfr, acc[0][nt], 0, 0, 0);
            acc[1][nt] = __builtin_amdgcn_mfma_f32_16x16x32_bf16(a1, bfr, acc[1][nt], 0, 0, 0);
        }
    }
    __syncthreads();   // all YT reads done before H1T(=YT) writes

    #pragma unroll
    for (int i = 0; i < 2; ++i) {
        const int o0 = m0 + 16 * i + 4 * q;
        #pragma unroll
        for (int nt = 0; nt < 4; ++nt) {
            const f32x4 v = acc[i][nt];
            bf16x4 hv;
            #pragma unroll
            for (int r = 0; r < 4; ++r) {
                float x = v[r] + B1s[o0 + r];
                hv[r] = (bf16)fmaxf(x, 0.f);
            }
            *(bf16x4*)(&YT[(nt * 16 + m) * YSTR + o0]) = hv;
        }
    }
    __syncthreads();

    // ---- layer 2 ----
    f32x4 acc2[2][4];
    #pragma unroll
    for (int i = 0; i < 2; ++i)
        #pragma unroll
        for (int nt = 0; nt < 4; ++nt) acc2[i][nt] = (f32x4){0.f, 0.f, 0.f, 0.f};

    #pragma unroll
    for (int kb = 0; kb < 4; ++kb) {
        const bf16x8 a0 = *(const bf16x8*)(w2b + (size_t)(m0 + m)      * H_ + kb * 32 + q * 8);
        const bf16x8 a1 = *(const bf16x8*)(w2b + (size_t)(m0 + 16 + m) * H_ + kb * 32 + q * 8);
        #pragma unroll
        for (int nt = 0; nt < 4; ++nt) {
            const bf16x8 bfr = *(const bf16x8*)(&YT[(nt * 16 + m) * YSTR + kb * 32 + q * 8]);
            acc2[0][nt] = __builtin_amdgcn_mfma_f32_16x16x32_bf16(a0, bfr, acc2[0][nt], 0, 0, 0);
            acc2[1][nt] = __builtin_amdgcn_mfma_f32_16x16x32_bf16(a1, bfr, acc2[1][nt], 0, 0, 0);
        }
    }
    __syncthreads();   // all H1T(=Ys) reads done before Ys fp32 writes

    // ---- epilogue: bias + relu -> Ys[o][l] ----
    #pragma unroll
    for (int i = 0; i < 2; ++i) {
        const int o0 = m0 + 16 * i + 4 * q;
        #pragma unroll
        for (int nt = 0; nt < 4; ++nt) {
            const f32x4 v = acc2[i][nt];
            #pragma unroll
            for (int r = 0; r < 4; ++r) {
                float x = v[r] + B2s[o0 + r];
                Ys[(o0 + r) * 68 + nt * 16 + m] = fmaxf(x, 0.f);
            }
        }
    }
    __syncthreads();

    // ---- coalesced float4 stores ----
    {
        const int rg = tid >> 4, c4 = (tid & 15) << 2;
        float* op = out + ((size_t)b * H_) * L_ + l0;
        #pragma unroll
        for (int v = 0; v < 8; ++v) {
            const int row = v * 16 + rg;
            const float4 val = *(const float4*)(&Ys[row * 68 + c4]);
            *(float4*)(op + (size_t)row * L_ + c4) = val;
        }
    }
}

// ---------------------------------------------------------------- launch ----
extern "C" void kernel_launch(void* const* d_in, const int* in_sizes, int n_in,
                              void* d_out, int out_size, void* d_ws, size_t ws_size,
                              hipStream_t stream) {
    const float* u   = (const float*)d_in[0];
    const float* lre = (const float*)d_in[1];
    const float* lim = (const float*)d_in[2];
    const float* wre = (const float*)d_in[3];
    const float* wim = (const float*)d_in[4];
    const float* dv  = (const float*)d_in[5];
    const float* w1  = (const float*)d_in[6];
    const float* b1  = (const float*)d_in[7];
    const float* w2  = (const float*)d_in[8];
    const float* b2  = (const float*)d_in[9];
    float* out = (float*)d_out;

    char* ws = (char*)d_ws;
    bf16* ybf = (bf16*)ws;   ws += (size_t)B_ * H_ * L_ * 2;   // 33.55 MB
    bf16* w1b = (bf16*)ws;   ws += H_ * H_ * 2;
    bf16* w2b = (bf16*)ws;   ws += H_ * H_ * 2;

    hipLaunchKernelGGL(k_ssm3, dim3(512), dim3(512), 0, stream,
                       u, lre, lim, wre, wim, dv, w1, w2, w1b, w2b, ybf);
    hipLaunchKernelGGL(k_mlp, dim3(B_ * (L_ / 64)), dim3(256), 0, stream,
                       ybf, w1b, w2b, b1, b2, out);
}

// Round 9
// 129.193 us; speedup vs baseline: 1.0689x; 1.0155x over previous
//
#include <hip/hip_runtime.h>
#include <hip/hip_bf16.h>

#define B_ 16
#define H_ 128
#define L_ 4096
#define N_ 64
#define DT_ 0.01f

typedef __bf16 bf16;
typedef __bf16 bf16x8 __attribute__((ext_vector_type(8)));
typedef __bf16 bf16x4 __attribute__((ext_vector_type(4)));
typedef float f32x4 __attribute__((ext_vector_type(4)));

#define USWZ(c, k) ((c) * 64 + (((((k) >> 4) ^ ((c) & 3)) << 4) | ((k) & 15)))
#define SSWZ(c, k) ((c) * 128 + (((((k) >> 4) ^ ((c) & 7)) << 4) | ((k) & 15)))

// ---------------------------------------------------------------- k_ssm3 ----
// 512 blocks x 512 threads, 2 blocks/CU. Closed-form P/Q MFMA A-fragments in
// registers; contributions kept FP32 in LDS (bf16 storage fails: scan
// amplifies contrib quantization by 1/(1-|A^64|) ~ 16x -> absmax 3.75, r8).
// Wave-0 serial scan overlapped with waves 1-7's S-independent T@U MFMAs.
__global__ __launch_bounds__(512, 4) void k_ssm3(
        const float* __restrict__ u,
        const float* __restrict__ lre, const float* __restrict__ lim,
        const float* __restrict__ wre, const float* __restrict__ wim,
        const float* __restrict__ dv,
        const float* __restrict__ w1, const float* __restrict__ w2,
        bf16* __restrict__ w1b, bf16* __restrict__ w2b,
        bf16* __restrict__ ybf) {
    alignas(16) __shared__ char smem[68352];
    bf16*  Ubf  = (bf16*)smem;                    //  8192 B
    float* Ctr  = (float*)(smem + 8192);          // 33280 B fp32 [row][c] stride 65 (aliased Yb)
    bf16*  Sbf  = (bf16*)(smem + 41472);          // 16384 B
    bf16*  Tm   = (bf16*)(smem + 57856);          //  9216 B
    float* lamS = (float*)(smem + 67072);         //  1024 B: [lr|li|wr|wi][64] (lr,li pre-scaled)
    float* taps = (float*)(smem + 68096);         //   256 B

    const int tid  = threadIdx.x;
    const int lane = tid & 63, wv = tid >> 6;     // wv in [0,8)
    const int cl   = lane & 15, q = lane >> 4;
    const int bId  = blockIdx.x;
    const int h    = bId & 127;
    const int bg   = bId >> 7;                    // [0,4)

    // ---- weight cast: 64 contiguous elements per block ----
    if (tid < 64) {
        if (bId < 256) w1b[bId * 64 + tid] = (bf16)w1[bId * 64 + tid];
        else           w2b[(bId - 256) * 64 + tid] = (bf16)w2[(bId - 256) * 64 + tid];
    }
    // ---- stage lambda/W for this h ----
    if (tid < 64) {
        lamS[tid]       = lre[h * 64 + tid] * DT_;
        lamS[64 + tid]  = lim[h * 64 + tid] * DT_;
        lamS[128 + tid] = wre[h * 64 + tid];
        lamS[192 + tid] = wim[h * 64 + tid];
    }
    __syncthreads();

    // ---- P fragments (MFMA-1 A-op) in regs: row = wv*16+cl ----
    bf16x8 pA0, pA1;
    {
        const int row = wv * 16 + cl;
        const int n = row & 63;
        const bool isIm = row >= 64;
        const float lr = lamS[n], li = lamS[64 + n];
        #pragma unroll
        for (int jj = 0; jj < 8; ++jj) {
            const float p0 = (float)(63 - (q * 8 + jj));
            const float e0 = __expf(p0 * lr);
            pA0[jj] = (bf16)(isIm ? e0 * __sinf(p0 * li) : e0 * __cosf(p0 * li));
            const float p1 = (float)(63 - (32 + q * 8 + jj));
            const float e1 = __expf(p1 * lr);
            pA1[jj] = (bf16)(isIm ? e1 * __sinf(p1 * li) : e1 * __cosf(p1 * li));
        }
    }
    // ---- Q fragments (MFMA-2 A-op) in regs: dlt = (wv>>1)*16+cl ----
    bf16x8 qA[4];
    {
        const float fd = (float)((wv >> 1) * 16 + cl + 1);   // dlt+1
        #pragma unroll
        for (int ks = 0; ks < 4; ++ks) {
            #pragma unroll
            for (int nn = 0; nn < 4; ++nn) {
                const int n = ks * 16 + q * 4 + nn;          // n = k>>1
                const float lr = lamS[n], li = lamS[64 + n];
                const float wr = lamS[128 + n], wi = lamS[192 + n];
                const float e  = __expf(fd * lr);
                const float cr = e * __cosf(fd * li), ci = e * __sinf(fd * li);
                qA[ks][2 * nn]     = (bf16)(wr * cr - wi * ci);
                qA[ks][2 * nn + 1] = (bf16)(-(wr * ci + wi * cr));
            }
        }
    }
    // ---- A^64 for the scan (lane = mode n) ----
    float a64r, a64i;
    {
        const float lr = lamS[lane], li = lamS[64 + lane];
        const float e = __expf(64.f * lr);
        a64r = e * __cosf(64.f * li);
        a64i = e * __sinf(64.f * li);
    }
    // ---- taps[dlt] = sum_n Re(W_n A_n^dlt): wave wv does dlt = wv*8+i ----
    {
        const float lr = lamS[lane], li = lamS[64 + lane];
        const float wr = lamS[128 + lane], wi = lamS[192 + lane];
        #pragma unroll
        for (int i = 0; i < 8; ++i) {
            const int dlt = wv * 8 + i;
            const float fd = (float)dlt;
            const float e = __expf(fd * lr);
            float t = wr * e * __cosf(fd * li) - wi * e * __sinf(fd * li);
            #pragma unroll
            for (int d = 1; d < 64; d <<= 1) t += __shfl_xor(t, d, 64);
            if (lane == 0) taps[dlt] = t;
        }
    }
    __syncthreads();

    // ---- Toeplitz Tm[dlt][j] = taps[dlt-j] (+d_h on diag) ----
    {
        const int dlt = tid >> 3, j0 = (tid & 7) << 3;
        const float dh = dv[h];
        bf16x8 t;
        #pragma unroll
        for (int e = 0; e < 8; ++e) {
            const int j = j0 + e;
            float v = (j <= dlt) ? taps[dlt - j] : 0.f;
            if (j == dlt) v += dh;
            t[e] = (bf16)v;
        }
        *(bf16x8*)(&Tm[dlt * 72 + j0]) = t;
    }

    // ---- 4 batches per block ----
    const int mt = wv >> 1, nt0 = (wv & 1) * 2;
    for (int it = 0; it < 4; ++it) {
        const int bh = (bg * 4 + it) * 128 + h;
        const float* __restrict__ up = u + (size_t)bh * L_;

        // stage u -> Ubf (coalesced float4 x2, bf16 swizzled)
        {
            const int c = tid >> 3, j0 = (tid & 7) << 3;
            const float4* src = (const float4*)(up + c * 64 + j0);
            const float4 f0 = src[0], f1 = src[1];
            bf16x8 t;
            t[0] = (bf16)f0.x; t[1] = (bf16)f0.y; t[2] = (bf16)f0.z; t[3] = (bf16)f0.w;
            t[4] = (bf16)f1.x; t[5] = (bf16)f1.y; t[6] = (bf16)f1.z; t[7] = (bf16)f1.w;
            *(bf16x8*)(&Ubf[USWZ(c, j0)]) = t;
        }
        __syncthreads();

        // MFMA-1: Ctr[row][c] = P @ U (fp32), wave wv owns rows [16wv,16wv+16)
        {
            f32x4 acc[4];
            #pragma unroll
            for (int nt = 0; nt < 4; ++nt) acc[nt] = (f32x4){0.f, 0.f, 0.f, 0.f};
            #pragma unroll
            for (int nt = 0; nt < 4; ++nt) {
                const int c = nt * 16 + cl;
                const bf16x8 b0 = *(const bf16x8*)(&Ubf[USWZ(c, q * 8)]);
                acc[nt] = __builtin_amdgcn_mfma_f32_16x16x32_bf16(pA0, b0, acc[nt], 0, 0, 0);
                const bf16x8 bq = *(const bf16x8*)(&Ubf[USWZ(c, 32 + q * 8)]);
                acc[nt] = __builtin_amdgcn_mfma_f32_16x16x32_bf16(pA1, bq, acc[nt], 0, 0, 0);
            }
            #pragma unroll
            for (int nt = 0; nt < 4; ++nt)
                #pragma unroll
                for (int r = 0; r < 4; ++r)
                    Ctr[(wv * 16 + q * 4 + r) * 65 + nt * 16 + cl] = acc[nt][r];
        }
        __syncthreads();

        // OVERLAPPED PHASE: wave 0 scans; waves 1-7 do the S-independent T@U
        f32x4 acc2[2];
        acc2[0] = (f32x4){0.f, 0.f, 0.f, 0.f};
        acc2[1] = (f32x4){0.f, 0.f, 0.f, 0.f};
        if (wv == 0) {
            float sr = 0.f, si = 0.f;
            #pragma unroll 8
            for (int c = 0; c < 64; ++c) {
                bf16* sp = &Sbf[SSWZ(c, 2 * lane)];
                sp[0] = (bf16)sr;
                sp[1] = (bf16)si;
                const float cr = Ctr[lane * 65 + c];
                const float ci = Ctr[(64 + lane) * 65 + c];
                const float nr = fmaf(a64r, sr, fmaf(-a64i, si, cr));
                const float ni = fmaf(a64r, si, fmaf(a64i, sr, ci));
                sr = nr; si = ni;
            }
        } else {
            #pragma unroll
            for (int ks = 0; ks < 2; ++ks) {
                const int k0 = ks * 32 + q * 8;
                const bf16x8 a = *(const bf16x8*)(&Tm[(mt * 16 + cl) * 72 + k0]);
                #pragma unroll
                for (int j = 0; j < 2; ++j) {
                    const int c = (nt0 + j) * 16 + cl;
                    const bf16x8 bfr = *(const bf16x8*)(&Ubf[USWZ(c, k0)]);
                    acc2[j] = __builtin_amdgcn_mfma_f32_16x16x32_bf16(a, bfr, acc2[j], 0, 0, 0);
                }
            }
        }
        __syncthreads();

        // wave 0 catches up on its T@U; then all waves: Q@S; write Yb
        if (wv == 0) {
            #pragma unroll
            for (int ks = 0; ks < 2; ++ks) {
                const int k0 = ks * 32 + q * 8;
                const bf16x8 a = *(const bf16x8*)(&Tm[(mt * 16 + cl) * 72 + k0]);
                #pragma unroll
                for (int j = 0; j < 2; ++j) {
                    const int c = (nt0 + j) * 16 + cl;
                    const bf16x8 bfr = *(const bf16x8*)(&Ubf[USWZ(c, k0)]);
                    acc2[j] = __builtin_amdgcn_mfma_f32_16x16x32_bf16(a, bfr, acc2[j], 0, 0, 0);
                }
            }
        }
        {
            #pragma unroll
            for (int ks = 0; ks < 4; ++ks) {
                const int k0 = ks * 32 + q * 8;
                #pragma unroll
                for (int j = 0; j < 2; ++j) {
                    const int c = (nt0 + j) * 16 + cl;
                    const bf16x8 bfr = *(const bf16x8*)(&Sbf[SSWZ(c, k0)]);
                    acc2[j] = __builtin_amdgcn_mfma_f32_16x16x32_bf16(qA[ks], bfr, acc2[j], 0, 0, 0);
                }
            }
            bf16* Yb = (bf16*)Ctr;   // Ctr dead after scan
            #pragma unroll
            for (int j = 0; j < 2; ++j) {
                const int c = (nt0 + j) * 16 + cl;
                bf16x4 yv;
                #pragma unroll
                for (int r = 0; r < 4; ++r) yv[r] = (bf16)acc2[j][r];
                *(bf16x4*)(&Yb[c * 72 + mt * 16 + q * 4]) = yv;
            }
        }
        __syncthreads();

        // coalesced y store (one bf16x8 per thread)
        {
            const bf16* Yb = (const bf16*)Ctr;
            const int c = tid >> 3, s0 = (tid & 7) << 3;
            const bf16x8 v = *(const bf16x8*)(&Yb[c * 72 + s0]);
            *(bf16x8*)(ybf + (size_t)bh * L_ + c * 64 + s0) = v;
        }
        __syncthreads();
    }
}

// ----------------------------------------------------------------- k_mlp ----
// Fused 2-layer MLP. Slim LDS (YT only, 18.4 KB) -> 6 blocks/CU.
#define YSTR 136
__global__ __launch_bounds__(256, 6) void k_mlp(
        const bf16* __restrict__ ybf,
        const bf16* __restrict__ w1b, const bf16* __restrict__ w2b,
        const float* __restrict__ b1, const float* __restrict__ b2,
        float* __restrict__ out) {
    __shared__ bf16 YT[64 * YSTR];    // y tile transposed [l][h]; reused as H1T
    __shared__ float B1s[H_], B2s[H_];

    const int tid = threadIdx.x;
    const int b   = blockIdx.x >> 6;
    const int lt  = blockIdx.x & 63;
    const int l0  = lt * 64;

    if (tid < H_) { B1s[tid] = b1[tid]; B2s[tid] = b2[tid]; }

    // ---- stage y tile transposed [l][h] ----
    {
        const int h  = tid >> 1;
        const int lh = (tid & 1) * 32;
        const bf16x8* src = (const bf16x8*)(ybf + ((size_t)b * H_ + h) * L_ + l0 + lh);
        #pragma unroll
        for (int v = 0; v < 4; ++v) {
            bf16x8 d = src[v];
            #pragma unroll
            for (int e = 0; e < 8; ++e) YT[(lh + v * 8 + e) * YSTR + h] = d[e];
        }
    }
    __syncthreads();

    const int lane = tid & 63;
    const int wv   = tid >> 6;
    const int m    = lane & 15;
    const int q    = lane >> 4;
    const int m0   = wv * 32;

    // ---- layer 1 ----
    f32x4 acc[2][4];
    #pragma unroll
    for (int i = 0; i < 2; ++i)
        #pragma unroll
        for (int nt = 0; nt < 4; ++nt) acc[i][nt] = (f32x4){0.f, 0.f, 0.f, 0.f};

    #pragma unroll
    for (int kb = 0; kb < 4; ++kb) {
        const bf16x8 a0 = *(const bf16x8*)(w1b + (size_t)(m0 + m)      * H_ + kb * 32 + q * 8);
        const bf16x8 a1 = *(const bf16x8*)(w1b + (size_t)(m0 + 16 + m) * H_ + kb * 32 + q * 8);
        #pragma unroll
        for (int nt = 0; nt < 4; ++nt) {
            const bf16x8 bfr = *(const bf16x8*)(&YT[(nt * 16 + m) * YSTR + kb * 32 + q * 8]);
            acc[0][nt] = __builtin_amdgcn_mfma_f32_16x16x32_bf16(a0, bfr, acc[0][nt], 0, 0, 0);
            acc[1][nt] = __builtin_amdgcn_mfma_f32_16x16x32_bf16(a1, bfr, acc[1][nt], 0, 0, 0);
        }
    }
    __syncthreads();   // all YT reads done before H1T(=YT) writes

    #pragma unroll
    for (int i = 0; i < 2; ++i) {
        const int o0 = m0 + 16 * i + 4 * q;
        #pragma unroll
        for (int nt = 0; nt < 4; ++nt) {
            const f32x4 v = acc[i][nt];
            bf16x4 hv;
            #pragma unroll
            for (int r = 0; r < 4; ++r) {
                float x = v[r] + B1s[o0 + r];
                hv[r] = (bf16)fmaxf(x, 0.f);
            }
            *(bf16x4*)(&YT[(nt * 16 + m) * YSTR + o0]) = hv;
        }
    }
    __syncthreads();

    // ---- layer 2 ----
    f32x4 acc2[2][4];
    #pragma unroll
    for (int i = 0; i < 2; ++i)
        #pragma unroll
        for (int nt = 0; nt < 4; ++nt) acc2[i][nt] = (f32x4){0.f, 0.f, 0.f, 0.f};

    #pragma unroll
    for (int kb = 0; kb < 4; ++kb) {
        const bf16x8 a0 = *(const bf16x8*)(w2b + (size_t)(m0 + m)      * H_ + kb * 32 + q * 8);
        const bf16x8 a1 = *(const bf16x8*)(w2b + (size_t)(m0 + 16 + m) * H_ + kb * 32 + q * 8);
        #pragma unroll
        for (int nt = 0; nt < 4; ++nt) {
            const bf16x8 bfr = *(const bf16x8*)(&YT[(nt * 16 + m) * YSTR + kb * 32 + q * 8]);
            acc2[0][nt] = __builtin_amdgcn_mfma_f32_16x16x32_bf16(a0, bfr, acc2[0][nt], 0, 0, 0);
            acc2[1][nt] = __builtin_amdgcn_mfma_f32_16x16x32_bf16(a1, bfr, acc2[1][nt], 0, 0, 0);
        }
    }

    // ---- epilogue: bias + relu + direct f32 stores ----
    #pragma unroll
    for (int i = 0; i < 2; ++i) {
        const int o0 = m0 + 16 * i + 4 * q;
        #pragma unroll
        for (int nt = 0; nt < 4; ++nt) {
            const f32x4 v = acc2[i][nt];
            #pragma unroll
            for (int r = 0; r < 4; ++r) {
                float x = v[r] + B2s[o0 + r];
                x = fmaxf(x, 0.f);
                out[((size_t)b * H_ + o0 + r) * L_ + l0 + nt * 16 + m] = x;
            }
        }
    }
}

// ---------------------------------------------------------------- launch ----
extern "C" void kernel_launch(void* const* d_in, const int* in_sizes, int n_in,
                              void* d_out, int out_size, void* d_ws, size_t ws_size,
                              hipStream_t stream) {
    const float* u   = (const float*)d_in[0];
    const float* lre = (const float*)d_in[1];
    const float* lim = (const float*)d_in[2];
    const float* wre = (const float*)d_in[3];
    const float* wim = (const float*)d_in[4];
    const float* dv  = (const float*)d_in[5];
    const float* w1  = (const float*)d_in[6];
    const float* b1  = (const float*)d_in[7];
    const float* w2  = (const float*)d_in[8];
    const float* b2  = (const float*)d_in[9];
    float* out = (float*)d_out;

    char* ws = (char*)d_ws;
    bf16* ybf = (bf16*)ws;   ws += (size_t)B_ * H_ * L_ * 2;   // 33.55 MB
    bf16* w1b = (bf16*)ws;   ws += H_ * H_ * 2;
    bf16* w2b = (bf16*)ws;   ws += H_ * H_ * 2;

    hipLaunchKernelGGL(k_ssm3, dim3(512), dim3(512), 0, stream,
                       u, lre, lim, wre, wim, dv, w1, w2, w1b, w2b, ybf);
    hipLaunchKernelGGL(k_mlp, dim3(B_ * (L_ / 64)), dim3(256), 0, stream,
                       ybf, w1b, w2b, b1, b2, out);
}